// Round 1
// baseline (876.054 us; speedup 1.0000x reference)
//
#include <hip/hip_runtime.h>

#define BB 4
#define CC 64
#define HH 128
#define WW 128
#define HW (HH * WW)

// Offset conv: y = conv3x3(concat(a, x2), wt) + bias
// wt: (18, 128, 3, 3), out: (B, 18, H, W)
// Block: 512 threads = 256 pixels x 2 channel-halves (half 0: a, half 1: x2)
__global__ __launch_bounds__(512) void off_conv_kernel(
    const float* __restrict__ a,
    const float* __restrict__ x2,
    const float* __restrict__ wt,
    const float* __restrict__ bias,
    float* __restrict__ out) {
  __shared__ float wk[128][18];
  __shared__ float red[256][19];  // pad 18->19: conflict-free reduction
  const int tid = threadIdx.x;
  const int lanepix = tid & 255;
  const int chalf = tid >> 8;  // wave-uniform (waves 0-3 vs 4-7)
  const int pix = blockIdx.x * 256 + lanepix;
  const int b = pix >> 14;
  const int hw = pix & (HW - 1);
  const int h = hw >> 7;
  const int w = hw & (WW - 1);

  float acc[18];
#pragma unroll
  for (int o = 0; o < 18; o++) acc[o] = (chalf == 0) ? bias[o] : 0.f;

  const float* pin = ((chalf == 0) ? a : x2) + (size_t)b * (CC * HW);
  const int cbase = chalf * 64;

  for (int k = 0; k < 9; k++) {
    __syncthreads();
    for (int i = tid; i < 18 * 128; i += 512) {
      int o = i / 128, c = i & 127;
      wk[c][o] = wt[(o * 128 + c) * 9 + k];
    }
    __syncthreads();
    const int dy = k / 3 - 1, dx = k - (k / 3) * 3 - 1;
    const int hh = h + dy, ww2 = w + dx;
    const bool valid = (hh >= 0) & (hh < HH) & (ww2 >= 0) & (ww2 < WW);
    const int idx = hh * WW + ww2;
#pragma unroll 4
    for (int c = 0; c < 64; c++) {
      float v = valid ? pin[c * HW + idx] : 0.f;
#pragma unroll
      for (int o = 0; o < 18; o++) acc[o] = fmaf(v, wk[cbase + c][o], acc[o]);
    }
  }

  __syncthreads();
  if (chalf == 1) {
#pragma unroll
    for (int o = 0; o < 18; o++) red[lanepix][o] = acc[o];
  }
  __syncthreads();
  if (chalf == 0) {
    float* po = out + (size_t)b * (18 * HW) + hw;
#pragma unroll
    for (int o = 0; o < 18; o++) po[o * HW] = acc[o] + red[lanepix][o];
  }
}

// Deformable conv: bilinear-sample x at (base + offset), then
// out[b,o,h,w] = sum_{c,k} samp[b,c,k,h,w] * wt[o,c,k] + bias[o]
// wt: (64, 64, 3, 3), offset layout: channel 2k = dy, 2k+1 = dx
// Block: 512 threads = 256 pixels x 2 output-halves (32 outputs each)
__global__ __launch_bounds__(512) void deform_conv_kernel(
    const float* __restrict__ x,
    const float* __restrict__ off,
    const float* __restrict__ wt,
    const float* __restrict__ bias,
    float* __restrict__ out) {
  __shared__ float wk[64][64];  // [c][o] for current tap
  const int tid = threadIdx.x;
  const int lanepix = tid & 255;
  const int ohalf = tid >> 8;  // wave-uniform
  const int obase = ohalf * 32;
  const int pix = blockIdx.x * 256 + lanepix;
  const int b = pix >> 14;
  const int hw = pix & (HW - 1);
  const int h = hw >> 7;
  const int w = hw & (WW - 1);

  float acc[32];
#pragma unroll
  for (int o = 0; o < 32; o++) acc[o] = bias[obase + o];

  const float* xb = x + (size_t)b * (CC * HW);
  const float* offb = off + (size_t)b * (18 * HW) + hw;

  for (int k = 0; k < 9; k++) {
    __syncthreads();
    for (int i = tid; i < 64 * 64; i += 512) {
      int c = i >> 6, o = i & 63;
      wk[c][o] = wt[(o * 64 + c) * 9 + k];
    }
    __syncthreads();

    const int ky = k / 3, kx = k - ky * 3;
    const float py = (float)(h - 1 + ky) + offb[(2 * k) * HW];
    const float px = (float)(w - 1 + kx) + offb[(2 * k + 1) * HW];
    const float y0f = floorf(py), x0f = floorf(px);
    const float ly = py - y0f, lx = px - x0f;
    const int y0 = (int)y0f, x0 = (int)x0f;
    const int y1 = y0 + 1, x1 = x0 + 1;
    float w00 = (1.f - ly) * (1.f - lx);
    float w01 = (1.f - ly) * lx;
    float w10 = ly * (1.f - lx);
    float w11 = ly * lx;
    if (y0 < 0 || y0 >= HH) { w00 = 0.f; w01 = 0.f; }
    if (y1 < 0 || y1 >= HH) { w10 = 0.f; w11 = 0.f; }
    if (x0 < 0 || x0 >= WW) { w00 = 0.f; w10 = 0.f; }
    if (x1 < 0 || x1 >= WW) { w01 = 0.f; w11 = 0.f; }
    const int cy0 = min(max(y0, 0), HH - 1), cy1 = min(max(y1, 0), HH - 1);
    const int cx0 = min(max(x0, 0), WW - 1), cx1 = min(max(x1, 0), WW - 1);
    const int i00 = cy0 * WW + cx0, i01 = cy0 * WW + cx1;
    const int i10 = cy1 * WW + cx0, i11 = cy1 * WW + cx1;

#pragma unroll 4
    for (int c = 0; c < 64; c++) {
      const float* xc = xb + c * HW;
      float s = xc[i00] * w00 + xc[i01] * w01 + xc[i10] * w10 + xc[i11] * w11;
      const float* wr = &wk[c][obase];
#pragma unroll
      for (int o = 0; o < 32; o++) acc[o] = fmaf(s, wr[o], acc[o]);
    }
  }

  float* ob = out + (size_t)b * (CC * HW) + hw;
#pragma unroll
  for (int o = 0; o < 32; o++) ob[(obase + o) * HW] = acc[o];
}

extern "C" void kernel_launch(void* const* d_in, const int* in_sizes, int n_in,
                              void* d_out, int out_size, void* d_ws, size_t ws_size,
                              hipStream_t stream) {
  const float* ref    = (const float*)d_in[0];
  const float* nbr    = (const float*)d_in[1];
  const float* w_off1 = (const float*)d_in[2];
  const float* b_off1 = (const float*)d_in[3];
  const float* w_d1   = (const float*)d_in[4];
  const float* b_d1   = (const float*)d_in[5];
  const float* w_off2 = (const float*)d_in[6];
  const float* b_off2 = (const float*)d_in[7];
  const float* w_d2   = (const float*)d_in[8];
  const float* b_d2   = (const float*)d_in[9];
  const float* w_off3 = (const float*)d_in[10];
  const float* b_off3 = (const float*)d_in[11];
  const float* w_d3   = (const float*)d_in[12];
  const float* b_d3   = (const float*)d_in[13];

  float* out = (float*)d_out;
  float* ws = (float*)d_ws;
  // ws layout: offsets (4*18*16384 = 1179648 f) + d2 (4*64*16384 = 4194304 f)
  // d1 lives in d_out (dead before the final deform writes the real output).
  float* off_buf = ws;
  float* d2 = ws + (size_t)BB * 18 * HW;
  float* d1 = out;

  const int nblk = BB * HW / 256;  // 256 blocks, 512 threads each

  off_conv_kernel<<<nblk, 512, 0, stream>>>(ref, nbr, w_off1, b_off1, off_buf);
  deform_conv_kernel<<<nblk, 512, 0, stream>>>(nbr, off_buf, w_d1, b_d1, d1);
  off_conv_kernel<<<nblk, 512, 0, stream>>>(ref, d1, w_off2, b_off2, off_buf);
  deform_conv_kernel<<<nblk, 512, 0, stream>>>(d1, off_buf, w_d2, b_d2, d2);
  off_conv_kernel<<<nblk, 512, 0, stream>>>(ref, d2, w_off3, b_off3, off_buf);
  deform_conv_kernel<<<nblk, 512, 0, stream>>>(d2, off_buf, w_d3, b_d3, out);
}

// Round 2
// 514.195 us; speedup vs baseline: 1.7037x; 1.7037x over previous
//
#include <hip/hip_runtime.h>

#define BB 4
#define CC 64
#define HH 128
#define WW 128
#define HW (HH * WW)

// Transpose weights for scalar-load-friendly access:
// deform: wd (64,64,3,3) -> td[k][c][64 o]          (stride 64 f = 256 B, 16B-aligned)
// offset: wo (18,128,3,3) -> to[k][c][20] (18 o + pad) (stride 80 B, 16B-aligned)
__global__ __launch_bounds__(256) void prep_weights(
    const float* __restrict__ wd, const float* __restrict__ wo,
    float* __restrict__ td, float* __restrict__ to) {
  int i = blockIdx.x * 256 + threadIdx.x;
  if (i < 64 * 64 * 9) {
    int o = i / 576, c = (i / 9) & 63, k = i % 9;
    td[(k * 64 + c) * 64 + o] = wd[i];
  }
  if (i < 18 * 128 * 9) {
    int o = i / 1152, c = (i / 9) & 127, k = i % 9;
    to[(k * 128 + c) * 20 + o] = wo[i];
  }
}

// Offset conv: y = conv3x3(concat(a, x2), w) + bias -> (B,18,H,W)
// Block 512 = 128 px x 4 c-quarters (32 input channels each). No per-tap
// barriers: weights come straight from global via s_load (uniform index).
__global__ __launch_bounds__(512, 4) void off_conv_kernel(
    const float* __restrict__ a, const float* __restrict__ x2,
    const float* __restrict__ to, const float* __restrict__ bias,
    float* __restrict__ out) {
  __shared__ float red[3][128][19];
  int bid = blockIdx.x;
  bid = (bid & 7) * (gridDim.x >> 3) + (bid >> 3);  // XCD-contiguous chunks
  const int tid = threadIdx.x;
  const int lp = tid & 127;
  const int cq = __builtin_amdgcn_readfirstlane(tid >> 7);  // wave-uniform
  const int cbase = cq * 32;
  const int pix = bid * 128 + lp;
  const int b = pix >> 14;
  const int hw = pix & (HW - 1);
  const int h = hw >> 7, w = hw & (WW - 1);

  const float* pin = ((cq < 2) ? a : x2) + (size_t)b * (CC * HW)
                     + (size_t)(cq & 1) * 32 * HW;

  float acc[18];
#pragma unroll
  for (int o = 0; o < 18; o++) acc[o] = 0.f;

  for (int k = 0; k < 9; k++) {
    const int ky = k / 3, kx = k - ky * 3;
    const int hh = h + ky - 1, ww2 = w + kx - 1;
    const bool valid = (hh >= 0) & (hh < HH) & (ww2 >= 0) & (ww2 < WW);
    const int idx = hh * WW + ww2;
#pragma unroll 4
    for (int c = 0; c < 32; c++) {
      float v = valid ? pin[c * HW + idx] : 0.f;
      const float* wr = to + (k * 128 + cbase + c) * 20;  // uniform -> s_load
#pragma unroll
      for (int o = 0; o < 18; o++) acc[o] = fmaf(v, wr[o], acc[o]);
    }
  }

  if (cq > 0) {
#pragma unroll
    for (int o = 0; o < 18; o++) red[cq - 1][lp][o] = acc[o];
  }
  __syncthreads();
  if (cq == 0) {
    float* po = out + (size_t)b * (18 * HW) + hw;
#pragma unroll
    for (int o = 0; o < 18; o++)
      po[o * HW] = acc[o] + red[0][lp][o] + red[1][lp][o] + red[2][lp][o]
                   + bias[o];
  }
}

// Deformable conv. Block 512 = 128 px x 4 o-quarters (16 outputs each).
// Gather-once: each o-quarter wave bilinear-samples its 16-channel slice into
// samp[c][px] LDS; all waves then consume all 64 channels. Weights via s_load.
__global__ __launch_bounds__(512, 4) void deform_conv_kernel(
    const float* __restrict__ x, const float* __restrict__ off,
    const float* __restrict__ td, const float* __restrict__ bias,
    float* __restrict__ out) {
  __shared__ float samp[64][128];
  int bid = blockIdx.x;
  bid = (bid & 7) * (gridDim.x >> 3) + (bid >> 3);
  const int tid = threadIdx.x;
  const int lp = tid & 127;
  const int oq = __builtin_amdgcn_readfirstlane(tid >> 7);  // wave-uniform
  const int obase = oq * 16;
  const int pix = bid * 128 + lp;
  const int b = pix >> 14;
  const int hw = pix & (HW - 1);
  const int h = hw >> 7, w = hw & (WW - 1);

  const float* xb = x + (size_t)b * (CC * HW);
  const float* offb = off + (size_t)b * (18 * HW) + hw;

  float acc[16];
#pragma unroll
  for (int o = 0; o < 16; o++) acc[o] = bias[obase + o];

  for (int k = 0; k < 9; k++) {
    if (k) __syncthreads();  // protect samp from overwrite
    const int ky = k / 3, kx = k - ky * 3;
    const float py = (float)(h - 1 + ky) + offb[(2 * k) * HW];
    const float px = (float)(w - 1 + kx) + offb[(2 * k + 1) * HW];
    const float y0f = floorf(py), x0f = floorf(px);
    const float ly = py - y0f, lx = px - x0f;
    const int y0 = (int)y0f, x0 = (int)x0f;
    const int y1 = y0 + 1, x1 = x0 + 1;
    float w00 = (1.f - ly) * (1.f - lx);
    float w01 = (1.f - ly) * lx;
    float w10 = ly * (1.f - lx);
    float w11 = ly * lx;
    if (y0 < 0 || y0 >= HH) { w00 = 0.f; w01 = 0.f; }
    if (y1 < 0 || y1 >= HH) { w10 = 0.f; w11 = 0.f; }
    if (x0 < 0 || x0 >= WW) { w00 = 0.f; w10 = 0.f; }
    if (x1 < 0 || x1 >= WW) { w01 = 0.f; w11 = 0.f; }
    const int cy0 = min(max(y0, 0), HH - 1), cy1 = min(max(y1, 0), HH - 1);
    const int cx0 = min(max(x0, 0), WW - 1), cx1 = min(max(x1, 0), WW - 1);
    const int i00 = cy0 * WW + cx0, i01 = cy0 * WW + cx1;
    const int i10 = cy1 * WW + cx0, i11 = cy1 * WW + cx1;

    // each wave samples its own 16-channel slice
#pragma unroll
    for (int i = 0; i < 16; i++) {
      const float* xc = xb + (size_t)(obase + i) * HW;
      float s = xc[i00] * w00 + xc[i01] * w01 + xc[i10] * w10 + xc[i11] * w11;
      samp[obase + i][lp] = s;
    }
    __syncthreads();

#pragma unroll 8
    for (int c = 0; c < 64; c++) {
      float s = samp[c][lp];
      const float* wr = td + ((k * 64 + c) << 6) + obase;  // uniform -> s_load
#pragma unroll
      for (int o = 0; o < 16; o++) acc[o] = fmaf(s, wr[o], acc[o]);
    }
  }

  float* ob = out + (size_t)b * (CC * HW) + hw;
#pragma unroll
  for (int o = 0; o < 16; o++) ob[(obase + o) * HW] = acc[o];
}

extern "C" void kernel_launch(void* const* d_in, const int* in_sizes, int n_in,
                              void* d_out, int out_size, void* d_ws, size_t ws_size,
                              hipStream_t stream) {
  const float* ref    = (const float*)d_in[0];
  const float* nbr    = (const float*)d_in[1];
  const float* w_off1 = (const float*)d_in[2];
  const float* b_off1 = (const float*)d_in[3];
  const float* w_d1   = (const float*)d_in[4];
  const float* b_d1   = (const float*)d_in[5];
  const float* w_off2 = (const float*)d_in[6];
  const float* b_off2 = (const float*)d_in[7];
  const float* w_d2   = (const float*)d_in[8];
  const float* b_d2   = (const float*)d_in[9];
  const float* w_off3 = (const float*)d_in[10];
  const float* b_off3 = (const float*)d_in[11];
  const float* w_d3   = (const float*)d_in[12];
  const float* b_d3   = (const float*)d_in[13];

  float* out = (float*)d_out;
  float* ws = (float*)d_ws;
  // ws layout (floats):
  // off_buf 1179648 | d2 4194304 | td1..3 3x36864 | to1..3 3x23040  (~22.2 MB)
  float* off_buf = ws;
  float* d2  = off_buf + (size_t)BB * 18 * HW;
  float* td1 = d2 + (size_t)BB * CC * HW;
  float* td2 = td1 + 36864;
  float* td3 = td2 + 36864;
  float* to1 = td3 + 36864;
  float* to2 = to1 + 23040;
  float* to3 = to2 + 23040;
  float* d1 = out;  // dead before the final deform writes the real output

  prep_weights<<<144, 256, 0, stream>>>(w_d1, w_off1, td1, to1);
  prep_weights<<<144, 256, 0, stream>>>(w_d2, w_off2, td2, to2);
  prep_weights<<<144, 256, 0, stream>>>(w_d3, w_off3, td3, to3);

  const int nblk = BB * HW / 128;  // 512 blocks, 512 threads each

  off_conv_kernel<<<nblk, 512, 0, stream>>>(ref, nbr, to1, b_off1, off_buf);
  deform_conv_kernel<<<nblk, 512, 0, stream>>>(nbr, off_buf, td1, b_d1, d1);
  off_conv_kernel<<<nblk, 512, 0, stream>>>(ref, d1, to2, b_off2, off_buf);
  deform_conv_kernel<<<nblk, 512, 0, stream>>>(d1, off_buf, td2, b_d2, d2);
  off_conv_kernel<<<nblk, 512, 0, stream>>>(ref, d2, to3, b_off3, off_buf);
  deform_conv_kernel<<<nblk, 512, 0, stream>>>(d2, off_buf, td3, b_d3, out);
}